// Round 8
// baseline (429.606 us; speedup 1.0000x reference)
//
#include <hip/hip_runtime.h>
#include <math.h>

#define C 64
#define NHEADS 4
#define DH 16
#define NN 262144   // H*W
#define NB 2
#define PB 512      // partial Gram blocks per batch
#define NT 2        // 256-col tiles per block (gram)
#define PREP 2      // probe repetition factor (visibility above 75us fills)
#define EPS 1e-12f

typedef __attribute__((ext_vector_type(8))) short short8v;     // 8 bf16
typedef __attribute__((ext_vector_type(8))) unsigned short ushort8v;
typedef __attribute__((ext_vector_type(4))) unsigned short ushort4v;
typedef __attribute__((ext_vector_type(4))) float f32x4;

static __device__ __forceinline__ unsigned short f2bf(float f) {
  union { float f; unsigned int u; } v; v.f = f;
  unsigned int r = v.u + 0x7fffu + ((v.u >> 16) & 1u);   // RNE round to bf16
  return (unsigned short)(r >> 16);
}

// ============ PROBE A1: gram, plain __syncthreads staging (R5 structure) ====
// Accumulates over PREP reps, stores 0.5*acc (keeps rep-0 MFMAs live, exact).
__global__ __launch_bounds__(256, 2) void gram_plain(const float* __restrict__ x,
                                                     float* __restrict__ Gc) {
  __shared__ unsigned short xs[C * 256];
  const int b = blockIdx.y;
  const int chunk = blockIdx.x;
  const float* xb = x + (size_t)b * C * NN;
  const int t = threadIdx.x;
  const int w = t >> 6, l = t & 63;
  const int lrow = l & 15, lhi = l >> 4;

  const int gA0 = (w >> 1) * 2, gA1 = gA0 + 1;
  const int gB0 = (w & 1) * 2,  gB1 = gB0 + 1;
  const int cA0 = gA0 * 16 + lrow, cA1 = gA1 * 16 + lrow;
  const int cB0 = gB0 * 16 + lrow, cB1 = gB1 * 16 + lrow;

  f32x4 acc0 = {0.f,0.f,0.f,0.f}, acc1 = {0.f,0.f,0.f,0.f};
  f32x4 acc2 = {0.f,0.f,0.f,0.f}, acc3 = {0.f,0.f,0.f,0.f};

  for (int rep = 0; rep < PREP; ++rep) {
    for (int tile = 0; tile < NT; ++tile) {
      const int j0 = (chunk * NT + tile) * 256;
      __syncthreads();
#pragma unroll
      for (int i = 0; i < 8; ++i) {
        const int oi = i * 256 + t;
        const int c = oi >> 5, oct = oi & 31;
        const float* src = xb + (size_t)c * NN + j0 + oct * 8;
        const float4 v0 = *reinterpret_cast<const float4*>(src);
        const float4 v1 = *reinterpret_cast<const float4*>(src + 4);
        ushort8v pk;
        pk[0] = f2bf(v0.x); pk[1] = f2bf(v0.y); pk[2] = f2bf(v0.z); pk[3] = f2bf(v0.w);
        pk[4] = f2bf(v1.x); pk[5] = f2bf(v1.y); pk[6] = f2bf(v1.z); pk[7] = f2bf(v1.w);
        *reinterpret_cast<ushort8v*>(&xs[c * 256 + ((oct ^ (c & 7)) << 3)]) = pk;
      }
      __syncthreads();
#pragma unroll
      for (int s = 0; s < 8; ++s) {
        const int o = s * 4 + lhi;
        const short8v fA0 = *reinterpret_cast<const short8v*>(&xs[cA0 * 256 + ((o ^ (cA0 & 7)) << 3)]);
        const short8v fA1 = *reinterpret_cast<const short8v*>(&xs[cA1 * 256 + ((o ^ (cA1 & 7)) << 3)]);
        const short8v fB0 = *reinterpret_cast<const short8v*>(&xs[cB0 * 256 + ((o ^ (cB0 & 7)) << 3)]);
        const short8v fB1 = *reinterpret_cast<const short8v*>(&xs[cB1 * 256 + ((o ^ (cB1 & 7)) << 3)]);
        acc0 = __builtin_amdgcn_mfma_f32_16x16x32_bf16(fA0, fB0, acc0, 0, 0, 0);
        acc1 = __builtin_amdgcn_mfma_f32_16x16x32_bf16(fA0, fB1, acc1, 0, 0, 0);
        acc2 = __builtin_amdgcn_mfma_f32_16x16x32_bf16(fA1, fB0, acc2, 0, 0, 0);
        acc3 = __builtin_amdgcn_mfma_f32_16x16x32_bf16(fA1, fB1, acc3, 0, 0, 0);
      }
    }
  }
  const float sc = 1.f / PREP;
  float* g = Gc + ((size_t)b * PB + chunk) * 4096;
#pragma unroll
  for (int r = 0; r < 4; ++r) {
    const int row = lhi * 4 + r;
    g[(gA0 * 16 + row) * 64 + gB0 * 16 + lrow] = acc0[r] * sc;
    g[(gA0 * 16 + row) * 64 + gB1 * 16 + lrow] = acc1[r] * sc;
    g[(gA1 * 16 + row) * 64 + gB0 * 16 + lrow] = acc2[r] * sc;
    g[(gA1 * 16 + row) * 64 + gB1 * 16 + lrow] = acc3[r] * sc;
  }
}

// ============ PROBE A2/A3: gram with reg-prefetch + raw barrier (R6/R7) =====
// EMIT_XBF=0 -> isolate prefetch vs gram_plain; =1 -> isolate xbf emit cost.
template <int EMIT_XBF>
__global__ __launch_bounds__(256, 3) void gram_pref_t(const float* __restrict__ x,
                                                      float* __restrict__ Gc,
                                                      unsigned short* __restrict__ xbf) {
  __shared__ unsigned short xs[C * 256];
  const int b = blockIdx.y;
  const int chunk = blockIdx.x;
  const float* xb = x + (size_t)b * C * NN;
  unsigned short* xbb = xbf + (size_t)b * C * NN;
  const int t = threadIdx.x;
  const int w = t >> 6, l = t & 63;
  const int lrow = l & 15, lhi = l >> 4;
  const int sc_ = t >> 5, soct = t & 31;

  const int gA0 = (w >> 1) * 2, gA1 = gA0 + 1;
  const int gB0 = (w & 1) * 2,  gB1 = gB0 + 1;
  const int cA0 = gA0 * 16 + lrow, cA1 = gA1 * 16 + lrow;
  const int cB0 = gB0 * 16 + lrow, cB1 = gB1 * 16 + lrow;

  f32x4 acc0 = {0.f,0.f,0.f,0.f}, acc1 = {0.f,0.f,0.f,0.f};
  f32x4 acc2 = {0.f,0.f,0.f,0.f}, acc3 = {0.f,0.f,0.f,0.f};

  float4 pre[8][2];
  for (int rep = 0; rep < PREP; ++rep) {
#pragma unroll
    for (int i = 0; i < 8; ++i) {
      const int c = i * 8 + sc_;
      const float* src = xb + (size_t)c * NN + chunk * (NT * 256) + soct * 8;
      pre[i][0] = *reinterpret_cast<const float4*>(src);
      pre[i][1] = *reinterpret_cast<const float4*>(src + 4);
    }
    for (int tile = 0; tile < NT; ++tile) {
      const int j0 = chunk * (NT * 256) + tile * 256;
#pragma unroll
      for (int i = 0; i < 8; ++i) {
        const int c = i * 8 + sc_;
        ushort8v pk;
        pk[0] = f2bf(pre[i][0].x); pk[1] = f2bf(pre[i][0].y);
        pk[2] = f2bf(pre[i][0].z); pk[3] = f2bf(pre[i][0].w);
        pk[4] = f2bf(pre[i][1].x); pk[5] = f2bf(pre[i][1].y);
        pk[6] = f2bf(pre[i][1].z); pk[7] = f2bf(pre[i][1].w);
        *reinterpret_cast<ushort8v*>(&xs[c * 256 + ((soct ^ (c & 7)) << 3)]) = pk;
        if (EMIT_XBF && rep == 0)
          *reinterpret_cast<ushort8v*>(&xbb[(size_t)c * NN + j0 + soct * 8]) = pk;
      }
      if (tile + 1 < NT) {
        const int jn = chunk * (NT * 256) + (tile + 1) * 256;
#pragma unroll
        for (int i = 0; i < 8; ++i) {
          const int c = i * 8 + sc_;
          const float* src = xb + (size_t)c * NN + jn + soct * 8;
          pre[i][0] = *reinterpret_cast<const float4*>(src);
          pre[i][1] = *reinterpret_cast<const float4*>(src + 4);
        }
      }
      asm volatile("s_waitcnt lgkmcnt(0)" ::: "memory");
      __builtin_amdgcn_s_barrier();
#pragma unroll
      for (int s = 0; s < 8; ++s) {
        const int o = s * 4 + lhi;
        const short8v fA0 = *reinterpret_cast<const short8v*>(&xs[cA0 * 256 + ((o ^ (cA0 & 7)) << 3)]);
        const short8v fA1 = *reinterpret_cast<const short8v*>(&xs[cA1 * 256 + ((o ^ (cA1 & 7)) << 3)]);
        const short8v fB0 = *reinterpret_cast<const short8v*>(&xs[cB0 * 256 + ((o ^ (cB0 & 7)) << 3)]);
        const short8v fB1 = *reinterpret_cast<const short8v*>(&xs[cB1 * 256 + ((o ^ (cB1 & 7)) << 3)]);
        acc0 = __builtin_amdgcn_mfma_f32_16x16x32_bf16(fA0, fB0, acc0, 0, 0, 0);
        acc1 = __builtin_amdgcn_mfma_f32_16x16x32_bf16(fA0, fB1, acc1, 0, 0, 0);
        acc2 = __builtin_amdgcn_mfma_f32_16x16x32_bf16(fA1, fB0, acc2, 0, 0, 0);
        acc3 = __builtin_amdgcn_mfma_f32_16x16x32_bf16(fA1, fB1, acc3, 0, 0, 0);
      }
      asm volatile("s_waitcnt lgkmcnt(0)" ::: "memory");
      __builtin_amdgcn_s_barrier();
    }
  }
  const float scl = 1.f / PREP;
  float* g = Gc + ((size_t)b * PB + chunk) * 4096;
#pragma unroll
  for (int r = 0; r < 4; ++r) {
    const int row = lhi * 4 + r;
    g[(gA0 * 16 + row) * 64 + gB0 * 16 + lrow] = acc0[r] * scl;
    g[(gA0 * 16 + row) * 64 + gB1 * 16 + lrow] = acc1[r] * scl;
    g[(gA1 * 16 + row) * 64 + gB0 * 16 + lrow] = acc2[r] * scl;
    g[(gA1 * 16 + row) * 64 + gB1 * 16 + lrow] = acc3[r] * scl;
  }
}

// ---------------- K1b: tree-reduce the PB partials -> G[b][4096] ----------------
__global__ __launch_bounds__(256) void reduce_kernel(const float* __restrict__ Gc,
                                                     float* __restrict__ G) {
  __shared__ float s[4][64];
  const int b = blockIdx.y;
  const int g = blockIdx.x;
  const int t = threadIdx.x;
  const int e = g * 64 + (t & 63);
  const int chunk = t >> 6;
  float sum = 0.f;
  for (int p = chunk; p < PB; p += 4)
    sum += Gc[((size_t)b * PB + p) * 4096 + e];
  s[chunk][t & 63] = sum;
  __syncthreads();
  if (t < 64) G[(size_t)b * 4096 + g * 64 + t] = s[0][t] + s[1][t] + s[2][t] + s[3][t];
}

// ---------------- K2: attention math -> E (bf16, includes +I) ----------------
__global__ __launch_bounds__(256) void attn_kernel(const float* __restrict__ G,
    const float* __restrict__ Wq, const float* __restrict__ Wk,
    const float* __restrict__ Wv, const float* __restrict__ Wp,
    const float* __restrict__ rescale, unsigned short* __restrict__ Ebf) {
  __shared__ float Gs[4096], GQt[4096], GKt[4096], T[4096];
  __shared__ float attnw[64][DH];
  __shared__ float nq[64], nk[64];
  const int b = blockIdx.x;
  const int t = threadIdx.x;

  for (int i = t; i < 4096; i += 256) Gs[i] = G[(size_t)b * 4096 + i];
  __syncthreads();
  for (int i = t; i < 4096; i += 256) {
    const int c = i >> 6, e = i & 63;
    float sq_ = 0.f, sk_ = 0.f;
    for (int c2 = 0; c2 < 64; ++c2) {
      const float g = Gs[c * 64 + c2];
      sq_ += g * Wq[e * 64 + c2];
      sk_ += g * Wk[e * 64 + c2];
    }
    GQt[c * 64 + e] = sq_;
    GKt[c * 64 + e] = sk_;
  }
  __syncthreads();
  if (t < 64) {
    float s = 0.f;
    for (int c2 = 0; c2 < 64; ++c2) s += Wq[t * 64 + c2] * GQt[c2 * 64 + t];
    nq[t] = sqrtf(fmaxf(s, 0.f));
  } else if (t < 128) {
    const int d = t - 64;
    float s = 0.f;
    for (int c2 = 0; c2 < 64; ++c2) s += Wk[d * 64 + c2] * GKt[c2 * 64 + d];
    nk[d] = sqrtf(fmaxf(s, 0.f));
  }
  __syncthreads();
  if (t < 64) {
    const int h = t >> 4;
    const float rs = rescale[h];
    const float nkd = fmaxf(nk[t], EPS);
    float logits[DH];
    float mx = -1e30f;
    for (int ee = 0; ee < DH; ++ee) {
      const int e = h * DH + ee;
      float num = 0.f;
      for (int c2 = 0; c2 < 64; ++c2) num += Wk[t * 64 + c2] * GQt[c2 * 64 + e];
      const float l = num / (nkd * fmaxf(nq[e], EPS)) * rs;
      logits[ee] = l;
      mx = fmaxf(mx, l);
    }
    float sum = 0.f;
    for (int ee = 0; ee < DH; ++ee) { const float p = expf(logits[ee] - mx); logits[ee] = p; sum += p; }
    const float inv = 1.f / sum;
    for (int ee = 0; ee < DH; ++ee) attnw[t][ee] = logits[ee] * inv;
  }
  __syncthreads();
  for (int i = t; i < 4096; i += 256) {
    const int r = i >> 6, c = i & 63;
    const int h = r >> 4;
    float s = 0.f;
    for (int e = 0; e < DH; ++e) s += attnw[r][e] * Wv[(h * DH + e) * 64 + c];
    T[i] = s;
  }
  __syncthreads();
  for (int i = t; i < 4096; i += 256) {
    const int r = i >> 6, c = i & 63;
    float s = (r == c) ? 1.f : 0.f;
    for (int m = 0; m < 64; ++m) s += Wp[r * 64 + m] * T[m * 64 + c];
    Ebf[(size_t)b * 4096 + i] = f2bf(s);
  }
}

// ============ PROBE B1: apply, LDS-staged from fp32 x (R6 structure) ========
__global__ __launch_bounds__(256, 4) void apply_lds(const float* __restrict__ x,
    const unsigned short* __restrict__ Ebf, const float* __restrict__ bp,
    float* __restrict__ out) {
  __shared__ unsigned short xt[128 * 64];
  const int b = blockIdx.y;
  const int n0 = blockIdx.x * 128;
  const float* xb = x + (size_t)b * C * NN;
  float* ob = out + (size_t)b * C * NN;
  const int t = threadIdx.x;
  const int w = t >> 6, l = t & 63;
  const int lrow = l & 15, lhi = l >> 4;

  short8v ef[4][2];
  const unsigned short* eb = Ebf + (size_t)b * 4096;
#pragma unroll
  for (int ot = 0; ot < 4; ++ot)
#pragma unroll
    for (int ks = 0; ks < 2; ++ks)
      ef[ot][ks] = *reinterpret_cast<const short8v*>(eb + (ot * 16 + lrow) * 64 + ks * 32 + lhi * 8);

  for (int rep = 0; rep < PREP; ++rep) {
    __syncthreads();   // WAR vs previous rep's LDS reads
#pragma unroll
    for (int h = 0; h < 2; ++h) {
      const int n = h * 64 + l;
#pragma unroll
      for (int i = 0; i < 4; ++i) {
        const int c0 = w * 16 + i * 4;
        const float v0 = xb[(size_t)(c0 + 0) * NN + n0 + n];
        const float v1 = xb[(size_t)(c0 + 1) * NN + n0 + n];
        const float v2 = xb[(size_t)(c0 + 2) * NN + n0 + n];
        const float v3 = xb[(size_t)(c0 + 3) * NN + n0 + n];
        ushort4v pk;
        pk[0] = f2bf(v0); pk[1] = f2bf(v1); pk[2] = f2bf(v2); pk[3] = f2bf(v3);
        const int q = c0 >> 2;
        *reinterpret_cast<ushort4v*>(
            &xt[n * 64 + ((((q >> 1) ^ (n & 7)) << 3) + (q & 1) * 4)]) = pk;
      }
    }
    __syncthreads();

    f32x4 acc[4][2];
#pragma unroll
    for (int ot = 0; ot < 4; ++ot)
#pragma unroll
      for (int nn = 0; nn < 2; ++nn) acc[ot][nn] = (f32x4){0.f, 0.f, 0.f, 0.f};

    const int nbase = w * 32;
#pragma unroll
    for (int nn = 0; nn < 2; ++nn) {
      const int n = nbase + nn * 16 + lrow;
#pragma unroll
      for (int ks = 0; ks < 2; ++ks) {
        const int s = ks * 4 + lhi;
        const short8v xf = *reinterpret_cast<const short8v*>(&xt[n * 64 + ((s ^ (n & 7)) << 3)]);
#pragma unroll
        for (int ot = 0; ot < 4; ++ot)
          acc[ot][nn] = __builtin_amdgcn_mfma_f32_16x16x32_bf16(xf, ef[ot][ks], acc[ot][nn], 0, 0, 0);
      }
    }
#pragma unroll
    for (int ot = 0; ot < 4; ++ot) {
      const int o = ot * 16 + lrow;
      const float bias = bp[o];
#pragma unroll
      for (int nn = 0; nn < 2; ++nn) {
        const int nb4 = n0 + nbase + nn * 16 + lhi * 4;
        float4 o4;
        o4.x = acc[ot][nn][0] + bias;
        o4.y = acc[ot][nn][1] + bias;
        o4.z = acc[ot][nn][2] + bias;
        o4.w = acc[ot][nn][3] + bias;
        *reinterpret_cast<float4*>(&ob[(size_t)o * NN + nb4]) = o4;
      }
    }
  }
}

// ============ PROBE B2: apply, LDS-free direct gather from xbf (R7) =========
__global__ __launch_bounds__(256, 3) void apply_direct(
    const unsigned short* __restrict__ xbf, const unsigned short* __restrict__ Ebf,
    const float* __restrict__ bp, float* __restrict__ out) {
  const int b = blockIdx.y;
  const int n0 = blockIdx.x * 128;
  const unsigned short* xb = xbf + (size_t)b * C * NN;
  float* ob = out + (size_t)b * C * NN;
  const int t = threadIdx.x;
  const int w = t >> 6, l = t & 63;
  const int lrow = l & 15, lhi = l >> 4;

  short8v ef[4][2];
  const unsigned short* eb = Ebf + (size_t)b * 4096;
#pragma unroll
  for (int ot = 0; ot < 4; ++ot)
#pragma unroll
    for (int ks = 0; ks < 2; ++ks)
      ef[ot][ks] = *reinterpret_cast<const short8v*>(eb + (ot * 16 + lrow) * 64 + ks * 32 + lhi * 8);

  for (int rep = 0; rep < PREP; ++rep) {
    f32x4 acc[4][2];
#pragma unroll
    for (int ot = 0; ot < 4; ++ot)
#pragma unroll
      for (int nn = 0; nn < 2; ++nn) acc[ot][nn] = (f32x4){0.f, 0.f, 0.f, 0.f};

    const int nbase = w * 32;
#pragma unroll
    for (int nn = 0; nn < 2; ++nn) {
      const int n = n0 + nbase + nn * 16 + lrow;
#pragma unroll
      for (int ks = 0; ks < 2; ++ks) {
        const unsigned short* src = xb + (size_t)(ks * 32 + lhi * 8) * NN + n;
        union { unsigned int u[4]; short8v v; } xf;
#pragma unroll
        for (int jj = 0; jj < 4; ++jj) {
          const unsigned int lo = src[(size_t)(2 * jj) * NN];
          const unsigned int hi = src[(size_t)(2 * jj + 1) * NN];
          xf.u[jj] = lo | (hi << 16);
        }
#pragma unroll
        for (int ot = 0; ot < 4; ++ot)
          acc[ot][nn] = __builtin_amdgcn_mfma_f32_16x16x32_bf16(xf.v, ef[ot][ks], acc[ot][nn], 0, 0, 0);
      }
    }
#pragma unroll
    for (int ot = 0; ot < 4; ++ot) {
      const int o = ot * 16 + lrow;
      const float bias = bp[o];
#pragma unroll
      for (int nn = 0; nn < 2; ++nn) {
        const int nb4 = n0 + nbase + nn * 16 + lhi * 4;
        float4 o4;
        o4.x = acc[ot][nn][0] + bias;
        o4.y = acc[ot][nn][1] + bias;
        o4.z = acc[ot][nn][2] + bias;
        o4.w = acc[ot][nn][3] + bias;
        *reinterpret_cast<float4*>(&ob[(size_t)o * NN + nb4]) = o4;
      }
    }
  }
}

extern "C" void kernel_launch(void* const* d_in, const int* in_sizes, int n_in,
                              void* d_out, int out_size, void* d_ws, size_t ws_size,
                              hipStream_t stream) {
  const float* x       = (const float*)d_in[0];
  const float* Wq      = (const float*)d_in[1];
  const float* Wk      = (const float*)d_in[2];
  const float* Wv      = (const float*)d_in[3];
  const float* Wp      = (const float*)d_in[4];
  const float* bp      = (const float*)d_in[5];
  const float* rescale = (const float*)d_in[6];
  float* out = (float*)d_out;

  float* Gc = out;                                                 // partials in d_out
  unsigned short* xbf = (unsigned short*)d_ws;                     // NB*C*NN bf16
  float* G = (float*)(xbf + (size_t)NB * C * NN);                  // NB*4096 f32
  unsigned short* Ebf = (unsigned short*)(G + (size_t)NB * 4096);  // NB*4096 bf16

  // PROBE round: 3 gram variants + 2 apply variants, each internally 2x.
  gram_plain<<<dim3(PB, NB), dim3(256), 0, stream>>>(x, Gc);
  gram_pref_t<0><<<dim3(PB, NB), dim3(256), 0, stream>>>(x, Gc, xbf);
  gram_pref_t<1><<<dim3(PB, NB), dim3(256), 0, stream>>>(x, Gc, xbf);
  reduce_kernel<<<dim3(64, NB), dim3(256), 0, stream>>>(Gc, G);
  attn_kernel<<<dim3(NB), dim3(256), 0, stream>>>(G, Wq, Wk, Wv, Wp, rescale, Ebf);
  apply_lds<<<dim3(2048, NB), dim3(256), 0, stream>>>(x, Ebf, bp, out);
  apply_direct<<<dim3(2048, NB), dim3(256), 0, stream>>>(xbf, Ebf, bp, out);
}

// Round 9
// 157.765 us; speedup vs baseline: 2.7231x; 2.7231x over previous
//
#include <hip/hip_runtime.h>
#include <math.h>

#define C 64
#define NHEADS 4
#define DH 16
#define NN 262144   // H*W
#define NB 2
#define PB 512      // partial Gram blocks per batch
#define NT 2        // 256-col tiles per block (gram)
#define EPS 1e-12f

typedef __attribute__((ext_vector_type(8))) short short8v;     // 8 bf16
typedef __attribute__((ext_vector_type(8))) unsigned short ushort8v;
typedef __attribute__((ext_vector_type(4))) float f32x4;

static __device__ __forceinline__ unsigned short f2bf(float f) {
  union { float f; unsigned int u; } v; v.f = f;
  unsigned int r = v.u + 0x7fffu + ((v.u >> 16) & 1u);   // RNE round to bf16
  return (unsigned short)(r >> 16);
}

// ---------------- K1: per-batch partial Gram via MFMA (R5-exact) ----------------
// grid (PB, NB), 256 threads = 4 waves. Block covers NT*256 n-cols.
// LDS tile: bf16 [64][256], 16B slot s of row c stored at (s ^ (c&7)).
__global__ __launch_bounds__(256, 2) void gram_kernel(const float* __restrict__ x,
                                                      float* __restrict__ Gc) {
  __shared__ unsigned short xs[C * 256];
  const int b = blockIdx.y;
  const int chunk = blockIdx.x;
  const float* xb = x + (size_t)b * C * NN;
  const int t = threadIdx.x;
  const int w = t >> 6, l = t & 63;
  const int lrow = l & 15, lhi = l >> 4;

  const int gA0 = (w >> 1) * 2, gA1 = gA0 + 1;
  const int gB0 = (w & 1) * 2,  gB1 = gB0 + 1;
  const int cA0 = gA0 * 16 + lrow, cA1 = gA1 * 16 + lrow;
  const int cB0 = gB0 * 16 + lrow, cB1 = gB1 * 16 + lrow;

  f32x4 acc0 = {0.f,0.f,0.f,0.f}, acc1 = {0.f,0.f,0.f,0.f};
  f32x4 acc2 = {0.f,0.f,0.f,0.f}, acc3 = {0.f,0.f,0.f,0.f};

  for (int tile = 0; tile < NT; ++tile) {
    const int j0 = (chunk * NT + tile) * 256;
    __syncthreads();
#pragma unroll
    for (int i = 0; i < 8; ++i) {
      const int oi = i * 256 + t;
      const int c = oi >> 5, oct = oi & 31;          // 32 octets (8 bf16) per row
      const float* src = xb + (size_t)c * NN + j0 + oct * 8;
      const float4 v0 = *reinterpret_cast<const float4*>(src);
      const float4 v1 = *reinterpret_cast<const float4*>(src + 4);
      ushort8v pk;
      pk[0] = f2bf(v0.x); pk[1] = f2bf(v0.y); pk[2] = f2bf(v0.z); pk[3] = f2bf(v0.w);
      pk[4] = f2bf(v1.x); pk[5] = f2bf(v1.y); pk[6] = f2bf(v1.z); pk[7] = f2bf(v1.w);
      *reinterpret_cast<ushort8v*>(&xs[c * 256 + ((oct ^ (c & 7)) << 3)]) = pk;
    }
    __syncthreads();
#pragma unroll
    for (int s = 0; s < 8; ++s) {
      const int o = s * 4 + lhi;                     // 16B slot holding k=s*32+lhi*8..+7
      const short8v fA0 = *reinterpret_cast<const short8v*>(&xs[cA0 * 256 + ((o ^ (cA0 & 7)) << 3)]);
      const short8v fA1 = *reinterpret_cast<const short8v*>(&xs[cA1 * 256 + ((o ^ (cA1 & 7)) << 3)]);
      const short8v fB0 = *reinterpret_cast<const short8v*>(&xs[cB0 * 256 + ((o ^ (cB0 & 7)) << 3)]);
      const short8v fB1 = *reinterpret_cast<const short8v*>(&xs[cB1 * 256 + ((o ^ (cB1 & 7)) << 3)]);
      acc0 = __builtin_amdgcn_mfma_f32_16x16x32_bf16(fA0, fB0, acc0, 0, 0, 0);
      acc1 = __builtin_amdgcn_mfma_f32_16x16x32_bf16(fA0, fB1, acc1, 0, 0, 0);
      acc2 = __builtin_amdgcn_mfma_f32_16x16x32_bf16(fA1, fB0, acc2, 0, 0, 0);
      acc3 = __builtin_amdgcn_mfma_f32_16x16x32_bf16(fA1, fB1, acc3, 0, 0, 0);
    }
  }
  // C/D layout: col = lane&15, row = (lane>>4)*4 + reg
  float* g = Gc + ((size_t)b * PB + chunk) * 4096;
#pragma unroll
  for (int r = 0; r < 4; ++r) {
    const int row = lhi * 4 + r;
    g[(gA0 * 16 + row) * 64 + gB0 * 16 + lrow] = acc0[r];
    g[(gA0 * 16 + row) * 64 + gB1 * 16 + lrow] = acc1[r];
    g[(gA1 * 16 + row) * 64 + gB0 * 16 + lrow] = acc2[r];
    g[(gA1 * 16 + row) * 64 + gB1 * 16 + lrow] = acc3[r];
  }
}

// ---------------- K1b: tree-reduce the PB partials -> G[b][4096] ----------------
__global__ __launch_bounds__(256) void reduce_kernel(const float* __restrict__ Gc,
                                                     float* __restrict__ G) {
  __shared__ float s[4][64];
  const int b = blockIdx.y;
  const int g = blockIdx.x;
  const int t = threadIdx.x;
  const int e = g * 64 + (t & 63);
  const int chunk = t >> 6;
  float sum = 0.f;
  for (int p = chunk; p < PB; p += 4)
    sum += Gc[((size_t)b * PB + p) * 4096 + e];
  s[chunk][t & 63] = sum;
  __syncthreads();
  if (t < 64) G[(size_t)b * 4096 + g * 64 + t] = s[0][t] + s[1][t] + s[2][t] + s[3][t];
}

// ---------------- K2: attention math -> E (bf16, includes +I) ----------------
__global__ __launch_bounds__(256) void attn_kernel(const float* __restrict__ G,
    const float* __restrict__ Wq, const float* __restrict__ Wk,
    const float* __restrict__ Wv, const float* __restrict__ Wp,
    const float* __restrict__ rescale, unsigned short* __restrict__ Ebf) {
  __shared__ float Gs[4096], GQt[4096], GKt[4096], T[4096];
  __shared__ float attnw[64][DH];
  __shared__ float nq[64], nk[64];
  const int b = blockIdx.x;
  const int t = threadIdx.x;

  for (int i = t; i < 4096; i += 256) Gs[i] = G[(size_t)b * 4096 + i];
  __syncthreads();
  for (int i = t; i < 4096; i += 256) {
    const int c = i >> 6, e = i & 63;
    float sq_ = 0.f, sk_ = 0.f;
    for (int c2 = 0; c2 < 64; ++c2) {
      const float g = Gs[c * 64 + c2];
      sq_ += g * Wq[e * 64 + c2];
      sk_ += g * Wk[e * 64 + c2];
    }
    GQt[c * 64 + e] = sq_;
    GKt[c * 64 + e] = sk_;
  }
  __syncthreads();
  if (t < 64) {
    float s = 0.f;
    for (int c2 = 0; c2 < 64; ++c2) s += Wq[t * 64 + c2] * GQt[c2 * 64 + t];
    nq[t] = sqrtf(fmaxf(s, 0.f));
  } else if (t < 128) {
    const int d = t - 64;
    float s = 0.f;
    for (int c2 = 0; c2 < 64; ++c2) s += Wk[d * 64 + c2] * GKt[c2 * 64 + d];
    nk[d] = sqrtf(fmaxf(s, 0.f));
  }
  __syncthreads();
  if (t < 64) {
    const int h = t >> 4;
    const float rs = rescale[h];
    const float nkd = fmaxf(nk[t], EPS);
    float logits[DH];
    float mx = -1e30f;
    for (int ee = 0; ee < DH; ++ee) {
      const int e = h * DH + ee;
      float num = 0.f;
      for (int c2 = 0; c2 < 64; ++c2) num += Wk[t * 64 + c2] * GQt[c2 * 64 + e];
      const float l = num / (nkd * fmaxf(nq[e], EPS)) * rs;
      logits[ee] = l;
      mx = fmaxf(mx, l);
    }
    float sum = 0.f;
    for (int ee = 0; ee < DH; ++ee) { const float p = expf(logits[ee] - mx); logits[ee] = p; sum += p; }
    const float inv = 1.f / sum;
    for (int ee = 0; ee < DH; ++ee) attnw[t][ee] = logits[ee] * inv;
  }
  __syncthreads();
  for (int i = t; i < 4096; i += 256) {
    const int r = i >> 6, c = i & 63;
    const int h = r >> 4;
    float s = 0.f;
    for (int e = 0; e < DH; ++e) s += attnw[r][e] * Wv[(h * DH + e) * 64 + c];
    T[i] = s;
  }
  __syncthreads();
  for (int i = t; i < 4096; i += 256) {
    const int r = i >> 6, c = i & 63;
    float s = (r == c) ? 1.f : 0.f;
    for (int m = 0; m < 64; ++m) s += Wp[r * 64 + m] * T[m * 64 + c];
    Ebf[(size_t)b * 4096 + i] = f2bf(s);
  }
}

// ---------------- K3: out = E * x + bp — persistent streaming MFMA ----------------
// grid (384, NB), 256 threads = 4 waves, 3 blocks/CU resident. NO LDS, NO barriers.
// Each wave grid-strides over 32-n chunks (~5-6 each): gathers x^T A-frags with 32
// independent dword loads (each instr = 4 x 64B coalesced segments), packs to bf16
// in-register, 16 MFMAs vs register-resident E, float4 stores (D[n][o] layout).
// Loads of chunk t+1 pipeline under MFMAs of chunk t (no cross-wave coupling).
__global__ __launch_bounds__(256, 3) void apply_stream(const float* __restrict__ x,
    const unsigned short* __restrict__ Ebf, const float* __restrict__ bp,
    float* __restrict__ out) {
  const int b = blockIdx.y;
  const float* xb = x + (size_t)b * C * NN;
  float* ob = out + (size_t)b * C * NN;
  const int t = threadIdx.x;
  const int w = t >> 6, l = t & 63;
  const int lrow = l & 15, lhi = l >> 4;

  // E fragments (B-operand): lane l, frag (ot,ks) holds E[ot*16+(l&15)][ks*32+(l>>4)*8 ..+7]
  short8v ef[4][2];
  const unsigned short* eb = Ebf + (size_t)b * 4096;
#pragma unroll
  for (int ot = 0; ot < 4; ++ot)
#pragma unroll
    for (int ks = 0; ks < 2; ++ks)
      ef[ot][ks] = *reinterpret_cast<const short8v*>(eb + (ot * 16 + lrow) * 64 + ks * 32 + lhi * 8);

  float bias[4];
#pragma unroll
  for (int ot = 0; ot < 4; ++ot) bias[ot] = bp[ot * 16 + lrow];

  const int gw = blockIdx.x * 4 + w;     // wave id within this batch
  const int NW = gridDim.x * 4;          // waves per batch

  for (int ch = gw; ch < NN / 32; ch += NW) {
    const int n0 = ch * 32;
    // gather A-frags: xf[nn][ks], lane = n (row), elems = c (k)
    short8v xf[2][2];
#pragma unroll
    for (int nn = 0; nn < 2; ++nn) {
      const int n = n0 + nn * 16 + lrow;
#pragma unroll
      for (int ks = 0; ks < 2; ++ks) {
        const float* src = xb + (size_t)(ks * 32 + lhi * 8) * NN + n;
        ushort8v pk;
#pragma unroll
        for (int j = 0; j < 8; ++j) pk[j] = f2bf(src[(size_t)j * NN]);
        xf[nn][ks] = *reinterpret_cast<short8v*>(&pk);
      }
    }
    f32x4 acc[4][2];
#pragma unroll
    for (int ot = 0; ot < 4; ++ot)
#pragma unroll
      for (int nn = 0; nn < 2; ++nn) acc[ot][nn] = (f32x4){0.f, 0.f, 0.f, 0.f};
#pragma unroll
    for (int nn = 0; nn < 2; ++nn)
#pragma unroll
      for (int ks = 0; ks < 2; ++ks)
#pragma unroll
        for (int ot = 0; ot < 4; ++ot)
          acc[ot][nn] = __builtin_amdgcn_mfma_f32_16x16x32_bf16(xf[nn][ks], ef[ot][ks], acc[ot][nn], 0, 0, 0);
    // store: D[n][o] -> o = ot*16+lrow, n = n0 + nn*16 + lhi*4 + r (r=0..3 -> float4)
#pragma unroll
    for (int ot = 0; ot < 4; ++ot) {
      const int o = ot * 16 + lrow;
#pragma unroll
      for (int nn = 0; nn < 2; ++nn) {
        float4 o4;
        o4.x = acc[ot][nn][0] + bias[ot];
        o4.y = acc[ot][nn][1] + bias[ot];
        o4.z = acc[ot][nn][2] + bias[ot];
        o4.w = acc[ot][nn][3] + bias[ot];
        *reinterpret_cast<float4*>(&ob[(size_t)o * NN + n0 + nn * 16 + lhi * 4]) = o4;
      }
    }
  }
}

extern "C" void kernel_launch(void* const* d_in, const int* in_sizes, int n_in,
                              void* d_out, int out_size, void* d_ws, size_t ws_size,
                              hipStream_t stream) {
  const float* x       = (const float*)d_in[0];
  const float* Wq      = (const float*)d_in[1];
  const float* Wk      = (const float*)d_in[2];
  const float* Wv      = (const float*)d_in[3];
  const float* Wp      = (const float*)d_in[4];
  const float* bp      = (const float*)d_in[5];
  const float* rescale = (const float*)d_in[6];
  float* out = (float*)d_out;

  // Partial Grams in d_out (16.8 MB; reduce consumes them before apply
  // overwrites — stream-ordered, R4/R5-proven). ws: G + E only.
  float* Gc = out;
  float* G  = (float*)d_ws;                                        // NB*4096 f32
  unsigned short* Ebf = (unsigned short*)(G + (size_t)NB * 4096);  // NB*4096 bf16

  gram_kernel<<<dim3(PB, NB), dim3(256), 0, stream>>>(x, Gc);
  reduce_kernel<<<dim3(64, NB), dim3(256), 0, stream>>>(Gc, G);
  attn_kernel<<<dim3(NB), dim3(256), 0, stream>>>(G, Wq, Wk, Wv, Wp, rescale, Ebf);
  apply_stream<<<dim3(384, NB), dim3(256), 0, stream>>>(x, Ebf, bp, out);
}